// Round 1
// baseline (931.676 us; speedup 1.0000x reference)
//
#include <hip/hip_runtime.h>

#define HW 65536
#define W_IMG 256
#define H_IMG 256
#define CIN 64
#define CHID 384
#define CQK 128

// ---------------- K1: 1x1 expansion GEMM ----------------
// hidden[co][p] = sum_ci wh[co][ci] * x[ci][p] + bh[co]
// block tile: CO=64 x PX=128, 256 threads, thread tile 8co x 4px
__global__ __launch_bounds__(256) void k1_expand(
    const float* __restrict__ x,      // [CIN][HW] (this batch)
    const float* __restrict__ wh,     // [CHID][CIN]
    const float* __restrict__ bh,     // [CHID]
    float* __restrict__ hidden)       // [CHID][HW]
{
    __shared__ float xs[CIN][128];
    __shared__ float wst[CIN][64];    // transposed [ci][co]
    const int pxbase = blockIdx.x * 128;
    const int cobase = blockIdx.y * 64;
    const int tid = threadIdx.x;

    // stage x tile (64x128 floats) as float4, coalesced
    #pragma unroll
    for (int r = 0; r < 8; ++r) {
        int idx = r * 256 + tid;            // float4 index 0..2047
        int ci = idx >> 5;
        int p4 = idx & 31;
        float4 v = *reinterpret_cast<const float4*>(&x[(size_t)ci * HW + pxbase + p4 * 4]);
        *reinterpret_cast<float4*>(&xs[ci][p4 * 4]) = v;
    }
    // stage weights transposed (LDS-write conflict-free: consecutive threads -> consecutive co)
    #pragma unroll
    for (int r = 0; r < 16; ++r) {
        int idx = r * 256 + tid;            // 0..4095
        int ci = idx >> 6;
        int co = idx & 63;
        wst[ci][co] = wh[(cobase + co) * CIN + ci];
    }
    __syncthreads();

    const int p = tid & 31;
    const int g = tid >> 5;
    const int px0 = p * 4;
    const int co0 = g * 8;

    float acc[8][4];
    #pragma unroll
    for (int i = 0; i < 8; ++i)
        #pragma unroll
        for (int j = 0; j < 4; ++j) acc[i][j] = 0.f;

    #pragma unroll 4
    for (int ci = 0; ci < CIN; ++ci) {
        float4 xv = *reinterpret_cast<const float4*>(&xs[ci][px0]);
        float4 w0 = *reinterpret_cast<const float4*>(&wst[ci][co0]);
        float4 w1 = *reinterpret_cast<const float4*>(&wst[ci][co0 + 4]);
        float wr[8] = {w0.x, w0.y, w0.z, w0.w, w1.x, w1.y, w1.z, w1.w};
        float xr[4] = {xv.x, xv.y, xv.z, xv.w};
        #pragma unroll
        for (int i = 0; i < 8; ++i)
            #pragma unroll
            for (int j = 0; j < 4; ++j)
                acc[i][j] += wr[i] * xr[j];
    }
    #pragma unroll
    for (int i = 0; i < 8; ++i) {
        int co = cobase + co0 + i;
        float b = bh[co];
        float4 o;
        o.x = acc[i][0] + b; o.y = acc[i][1] + b;
        o.z = acc[i][2] + b; o.w = acc[i][3] + b;
        *reinterpret_cast<float4*>(&hidden[(size_t)co * HW + pxbase + px0]) = o;
    }
}

// ---------------- K2: fused depthwise 3x3 + 8x8 circular conv + v-mul ----------------
// block = (strip of 8 rows, channel c in [0,128)); 256 threads
__global__ __launch_bounds__(256) void k2_fused(
    const float* __restrict__ hidden,  // [CHID][HW]
    const float* __restrict__ wdw,     // [CHID][9]
    const float* __restrict__ bdw,     // [CHID]
    float* __restrict__ vout)          // [CQK][HW]
{
    __shared__ float hs[3][10][258];   // rows r0-1..r0+8, w stored at index w+1 (w=-1..256)
    __shared__ float qs[8][256];
    __shared__ float ks[8][256];
    __shared__ float vs[8][256];
    __shared__ float wws[3][9];
    __shared__ float bbs[3];

    const int c  = blockIdx.y;         // qkv channel 0..127
    const int r0 = blockIdx.x * 8;
    const int tid = threadIdx.x;

    if (tid < 27) wws[tid / 9][tid % 9] = wdw[(c + (tid / 9) * CQK) * 9 + (tid % 9)];
    if (tid >= 32 && tid < 35) bbs[tid - 32] = bdw[c + (tid - 32) * CQK];

    // stage hidden channels {c, c+128, c+256}, 10 rows each, with w halo
    for (int idx = tid; idx < 3 * 10 * 258; idx += 256) {
        int ch  = idx / 2580;
        int rem = idx - ch * 2580;
        int lr  = rem / 258;
        int w   = rem - lr * 258 - 1;
        int gr  = r0 - 1 + lr;
        float v = 0.f;
        if (gr >= 0 && gr < H_IMG && w >= 0 && w < W_IMG)
            v = hidden[(size_t)(c + ch * CQK) * HW + gr * W_IMG + w];
        hs[ch][lr][w + 1] = v;
    }
    __syncthreads();

    // depthwise 3x3 -> q,k,v rows (output row `row` = global r0+row needs local rows row..row+2)
    for (int idx = tid; idx < 3 * 8 * 256; idx += 256) {
        int ch  = idx >> 11;
        int rem = idx & 2047;
        int row = rem >> 8;
        int w   = rem & 255;
        float a = bbs[ch];
        #pragma unroll
        for (int ky = 0; ky < 3; ++ky)
            #pragma unroll
            for (int kx = 0; kx < 3; ++kx)
                a += hs[ch][row + ky][w + kx] * wws[ch][ky * 3 + kx];
        if (ch == 0)      qs[row][w] = a;
        else if (ch == 1) ks[row][w] = a;
        else              vs[row][w] = a;
    }
    __syncthreads();

    // 8x8 circular conv per 64-px segment: out[i,j] = sum_{s,t} k[s,t]*q[(i-s)&7,(j-t)&7]
    const int row = tid >> 5;
    const int seg = (tid >> 3) & 3;
    const int i   = tid & 7;
    const float* qseg = &qs[row][seg * 64];
    const float* kseg = &ks[row][seg * 64];

    float acc[8];
    #pragma unroll
    for (int j = 0; j < 8; ++j) acc[j] = 0.f;

    #pragma unroll
    for (int s = 0; s < 8; ++s) {
        int qr = (i - s) & 7;
        float4 ka = *reinterpret_cast<const float4*>(&kseg[s * 8]);
        float4 kb = *reinterpret_cast<const float4*>(&kseg[s * 8 + 4]);
        float4 qa = *reinterpret_cast<const float4*>(&qseg[qr * 8]);
        float4 qb = *reinterpret_cast<const float4*>(&qseg[qr * 8 + 4]);
        float kr[8] = {ka.x, ka.y, ka.z, ka.w, kb.x, kb.y, kb.z, kb.w};
        float qv[8] = {qa.x, qa.y, qa.z, qa.w, qb.x, qb.y, qb.z, qb.w};
        #pragma unroll
        for (int t = 0; t < 8; ++t)
            #pragma unroll
            for (int j = 0; j < 8; ++j)
                acc[j] += kr[t] * qv[(j - t) & 7];
    }

    const float* vrow = &vs[row][seg * 64 + i * 8];
    float4 o0, o1;
    o0.x = acc[0] * vrow[0]; o0.y = acc[1] * vrow[1];
    o0.z = acc[2] * vrow[2]; o0.w = acc[3] * vrow[3];
    o1.x = acc[4] * vrow[4]; o1.y = acc[5] * vrow[5];
    o1.z = acc[6] * vrow[6]; o1.w = acc[7] * vrow[7];
    float* dst = &vout[(size_t)c * HW + (r0 + row) * W_IMG + seg * 64 + i * 8];
    *reinterpret_cast<float4*>(dst)     = o0;
    *reinterpret_cast<float4*>(dst + 4) = o1;
}

// ---------------- K3: 1x1 projection GEMM ----------------
// out[co][p] = sum_c wo[co][c] * vout[c][p] + bo[co];  CO=64 (all) x PX=64 tile
__global__ __launch_bounds__(256) void k3_project(
    const float* __restrict__ vout,  // [CQK][HW]
    const float* __restrict__ wo,    // [64][CQK]
    const float* __restrict__ bo,    // [64]
    float* __restrict__ out)         // [64][HW]
{
    __shared__ float vsh[CQK][64];
    __shared__ float wsh[CQK][64];   // transposed [c][co]
    const int pxbase = blockIdx.x * 64;
    const int tid = threadIdx.x;

    #pragma unroll
    for (int r = 0; r < 8; ++r) {
        int idx = r * 256 + tid;        // float4 index 0..2047
        int cc = idx >> 4;
        int p4 = idx & 15;
        *reinterpret_cast<float4*>(&vsh[cc][p4 * 4]) =
            *reinterpret_cast<const float4*>(&vout[(size_t)cc * HW + pxbase + p4 * 4]);
    }
    #pragma unroll
    for (int r = 0; r < 32; ++r) {
        int idx = r * 256 + tid;        // 0..8191
        int cc = idx >> 6;
        int co = idx & 63;
        wsh[cc][co] = wo[co * CQK + cc];
    }
    __syncthreads();

    const int p = tid & 15, g = tid >> 4;
    const int px0 = p * 4, co0 = g * 4;

    float acc[4][4];
    #pragma unroll
    for (int i = 0; i < 4; ++i)
        #pragma unroll
        for (int j = 0; j < 4; ++j) acc[i][j] = 0.f;

    #pragma unroll 4
    for (int cc = 0; cc < CQK; ++cc) {
        float4 xv = *reinterpret_cast<const float4*>(&vsh[cc][px0]);
        float4 wv = *reinterpret_cast<const float4*>(&wsh[cc][co0]);
        float wr[4] = {wv.x, wv.y, wv.z, wv.w};
        float xr[4] = {xv.x, xv.y, xv.z, xv.w};
        #pragma unroll
        for (int i = 0; i < 4; ++i)
            #pragma unroll
            for (int j = 0; j < 4; ++j)
                acc[i][j] += wr[i] * xr[j];
    }
    #pragma unroll
    for (int i = 0; i < 4; ++i) {
        int co = co0 + i;
        float b = bo[co];
        float4 o;
        o.x = acc[i][0] + b; o.y = acc[i][1] + b;
        o.z = acc[i][2] + b; o.w = acc[i][3] + b;
        *reinterpret_cast<float4*>(&out[(size_t)co * HW + pxbase + px0]) = o;
    }
}

extern "C" void kernel_launch(void* const* d_in, const int* in_sizes, int n_in,
                              void* d_out, int out_size, void* d_ws, size_t ws_size,
                              hipStream_t stream) {
    const float* x   = (const float*)d_in[0];
    const float* wh  = (const float*)d_in[1];
    const float* bh  = (const float*)d_in[2];
    const float* wdw = (const float*)d_in[3];
    const float* bdw = (const float*)d_in[4];
    const float* wo  = (const float*)d_in[5];
    const float* bo  = (const float*)d_in[6];
    float* out = (float*)d_out;

    float* hidden = (float*)d_ws;                       // CHID*HW floats = 100.7 MB
    float* vout   = hidden + (size_t)CHID * HW;         // CQK*HW floats  =  33.6 MB

    for (int b = 0; b < 4; ++b) {
        const float* xb = x + (size_t)b * CIN * HW;
        float* ob       = out + (size_t)b * CIN * HW;
        k1_expand <<<dim3(HW / 128, CHID / 64), 256, 0, stream>>>(xb, wh, bh, hidden);
        k2_fused  <<<dim3(H_IMG / 8, CQK),      256, 0, stream>>>(hidden, wdw, bdw, vout);
        k3_project<<<dim3(HW / 64),             256, 0, stream>>>(vout, wo, bo, ob);
    }
}

// Round 2
// 640.114 us; speedup vs baseline: 1.4555x; 1.4555x over previous
//
#include <hip/hip_runtime.h>

#define HW 65536
#define W_IMG 256
#define H_IMG 256
#define CIN 64
#define CHID 384
#define CQK 128

// K2 LDS layout: qk[ch][row][seg][68] flattened (stride 68 breaks bank aliasing)
#define QK_CH_STRIDE 2176   // 8*272
#define QK_ROW_STRIDE 272   // 4*68
#define QK_SEG_STRIDE 68

// ---------------- K1: 1x1 expansion GEMM ----------------
__global__ __launch_bounds__(256) void k1_expand(
    const float* __restrict__ x_base,    // [B][CIN][HW]
    const float* __restrict__ wh,        // [CHID][CIN]
    const float* __restrict__ bh,        // [CHID]
    float* __restrict__ hidden_base,     // [B][CHID][HW]
    size_t x_bstride, size_t hid_bstride)
{
    __shared__ float xs[CIN][128];
    __shared__ float wst[CIN][64];
    const float* x = x_base + blockIdx.z * x_bstride;
    float* hidden  = hidden_base + blockIdx.z * hid_bstride;
    const int pxbase = blockIdx.x * 128;
    const int cobase = blockIdx.y * 64;
    const int tid = threadIdx.x;

    #pragma unroll
    for (int r = 0; r < 8; ++r) {
        int idx = r * 256 + tid;
        int ci = idx >> 5;
        int p4 = idx & 31;
        float4 v = *reinterpret_cast<const float4*>(&x[(size_t)ci * HW + pxbase + p4 * 4]);
        *reinterpret_cast<float4*>(&xs[ci][p4 * 4]) = v;
    }
    #pragma unroll
    for (int r = 0; r < 16; ++r) {
        int idx = r * 256 + tid;
        int ci = idx >> 6;
        int co = idx & 63;
        wst[ci][co] = wh[(cobase + co) * CIN + ci];
    }
    __syncthreads();

    const int p = tid & 31;
    const int g = tid >> 5;
    const int px0 = p * 4;
    const int co0 = g * 8;

    float acc[8][4];
    #pragma unroll
    for (int i = 0; i < 8; ++i)
        #pragma unroll
        for (int j = 0; j < 4; ++j) acc[i][j] = 0.f;

    #pragma unroll 4
    for (int ci = 0; ci < CIN; ++ci) {
        float4 xv = *reinterpret_cast<const float4*>(&xs[ci][px0]);
        float4 w0 = *reinterpret_cast<const float4*>(&wst[ci][co0]);
        float4 w1 = *reinterpret_cast<const float4*>(&wst[ci][co0 + 4]);
        float wr[8] = {w0.x, w0.y, w0.z, w0.w, w1.x, w1.y, w1.z, w1.w};
        float xr[4] = {xv.x, xv.y, xv.z, xv.w};
        #pragma unroll
        for (int i = 0; i < 8; ++i)
            #pragma unroll
            for (int j = 0; j < 4; ++j)
                acc[i][j] += wr[i] * xr[j];
    }
    #pragma unroll
    for (int i = 0; i < 8; ++i) {
        int co = cobase + co0 + i;
        float b = bh[co];
        float4 o;
        o.x = acc[i][0] + b; o.y = acc[i][1] + b;
        o.z = acc[i][2] + b; o.w = acc[i][3] + b;
        *reinterpret_cast<float4*>(&hidden[(size_t)co * HW + pxbase + px0]) = o;
    }
}

// ---------------- K2: fused depthwise 3x3 + 8x8 circular conv + v-mul ----------------
// block = (strip of 8 rows, channel c); 256 threads; no raw-hidden LDS stage.
__global__ __launch_bounds__(256) void k2_fused(
    const float* __restrict__ hidden_base,  // [B][CHID][HW]
    const float* __restrict__ wdw,          // [CHID][9]
    const float* __restrict__ bdw,          // [CHID]
    float* __restrict__ vout_base,          // [B][CQK][HW]
    size_t hid_bstride, size_t vout_bstride)
{
    __shared__ float qk[2 * QK_CH_STRIDE];

    const float* hidden = hidden_base + blockIdx.z * hid_bstride;
    float* vout         = vout_base + blockIdx.z * vout_bstride;

    const int c  = blockIdx.y;          // qkv channel 0..127
    const int r0 = blockIdx.x * 8;
    const int tid = threadIdx.x;
    const int w   = tid;                // column 0..255
    const int segw = w >> 6;
    const int tw   = w & 63;

    // ---- phase 1: depthwise for q (ch 0) and k (ch 1), column w, rows r0..r0+7
    #pragma unroll
    for (int ch = 0; ch < 2; ++ch) {
        const float* hb = hidden + (size_t)(c + ch * CQK) * HW;
        const float* wv = wdw + (c + ch * CQK) * 9;   // block-uniform -> scalar loads
        const float bias = bdw[c + ch * CQK];
        const float w0 = wv[0], w1 = wv[1], w2 = wv[2];
        const float w3 = wv[3], w4 = wv[4], w5 = wv[5];
        const float w6 = wv[6], w7 = wv[7], w8 = wv[8];

        float am, a0, ap, bm, b0, bp, cm, c0, cp;
        {   // row r0-1
            int gr = r0 - 1;
            if (gr >= 0) {
                const float* rb = hb + (size_t)gr * W_IMG;
                am = (w > 0) ? rb[w - 1] : 0.f; a0 = rb[w]; ap = (w < 255) ? rb[w + 1] : 0.f;
            } else { am = a0 = ap = 0.f; }
        }
        {   // row r0
            const float* rb = hb + (size_t)r0 * W_IMG;
            bm = (w > 0) ? rb[w - 1] : 0.f; b0 = rb[w]; bp = (w < 255) ? rb[w + 1] : 0.f;
        }
        #pragma unroll
        for (int r = 0; r < 8; ++r) {
            int gr = r0 + r + 1;
            if (gr < H_IMG) {
                const float* rb = hb + (size_t)gr * W_IMG;
                cm = (w > 0) ? rb[w - 1] : 0.f; c0 = rb[w]; cp = (w < 255) ? rb[w + 1] : 0.f;
            } else { cm = c0 = cp = 0.f; }
            float a = bias + am * w0 + a0 * w1 + ap * w2
                           + bm * w3 + b0 * w4 + bp * w5
                           + cm * w6 + c0 * w7 + cp * w8;
            qk[ch * QK_CH_STRIDE + r * QK_ROW_STRIDE + segw * QK_SEG_STRIDE + tw] = a;
            am = bm; a0 = b0; ap = bp;
            bm = cm; b0 = c0; bp = cp;
        }
    }
    __syncthreads();

    // ---- phase 2: 8x8 circular conv + inline v depthwise + multiply
    const int row = tid >> 5;           // 0..7
    const int seg = (tid >> 3) & 3;     // 0..3
    const int i   = tid & 7;            // output patch-row

    const float* qb = &qk[row * QK_ROW_STRIDE + seg * QK_SEG_STRIDE];
    const float* kb = &qk[QK_CH_STRIDE + row * QK_ROW_STRIDE + seg * QK_SEG_STRIDE];

    float acc[8];
    #pragma unroll
    for (int j = 0; j < 8; ++j) acc[j] = 0.f;

    #pragma unroll
    for (int s = 0; s < 8; ++s) {
        int qr = (i - s) & 7;
        float4 ka = *reinterpret_cast<const float4*>(&kb[s * 8]);
        float4 kc = *reinterpret_cast<const float4*>(&kb[s * 8 + 4]);
        float4 qa = *reinterpret_cast<const float4*>(&qb[qr * 8]);
        float4 qc = *reinterpret_cast<const float4*>(&qb[qr * 8 + 4]);
        float kr[8] = {ka.x, ka.y, ka.z, ka.w, kc.x, kc.y, kc.z, kc.w};
        float qv[8] = {qa.x, qa.y, qa.z, qa.w, qc.x, qc.y, qc.z, qc.w};
        #pragma unroll
        for (int t = 0; t < 8; ++t)
            #pragma unroll
            for (int j = 0; j < 8; ++j)
                acc[j] += kr[t] * qv[(j - t) & 7];
    }

    // v depthwise for this thread's 8 output pixels
    const float* hbv = hidden + (size_t)(c + 2 * CQK) * HW;
    const float* wvv = wdw + (c + 2 * CQK) * 9;
    const float vbias = bdw[c + 2 * CQK];
    const int gr  = r0 + row;
    const int wp0 = seg * 64 + i * 8;     // output columns wp0..wp0+7

    float vc[8];
    #pragma unroll
    for (int j = 0; j < 8; ++j) vc[j] = vbias;
    #pragma unroll
    for (int ky = 0; ky < 3; ++ky) {
        int grr = gr + ky - 1;
        float kw0 = wvv[ky * 3], kw1 = wvv[ky * 3 + 1], kw2 = wvv[ky * 3 + 2];
        if ((unsigned)grr < H_IMG) {
            const float* rb = hbv + (size_t)grr * W_IMG;
            float4 A = *reinterpret_cast<const float4*>(&rb[wp0]);
            float4 Bv = *reinterpret_cast<const float4*>(&rb[wp0 + 4]);
            float h[10];
            h[1] = A.x; h[2] = A.y; h[3] = A.z; h[4] = A.w;
            h[5] = Bv.x; h[6] = Bv.y; h[7] = Bv.z; h[8] = Bv.w;
            h[0] = (wp0 > 0)   ? rb[wp0 - 1] : 0.f;
            h[9] = (wp0 < 248) ? rb[wp0 + 8] : 0.f;
            #pragma unroll
            for (int j = 0; j < 8; ++j)
                vc[j] += h[j] * kw0 + h[j + 1] * kw1 + h[j + 2] * kw2;
        }
    }

    float* dst = &vout[(size_t)c * HW + (size_t)gr * W_IMG + wp0];
    float4 o0, o1;
    o0.x = acc[0] * vc[0]; o0.y = acc[1] * vc[1];
    o0.z = acc[2] * vc[2]; o0.w = acc[3] * vc[3];
    o1.x = acc[4] * vc[4]; o1.y = acc[5] * vc[5];
    o1.z = acc[6] * vc[6]; o1.w = acc[7] * vc[7];
    *reinterpret_cast<float4*>(dst)     = o0;
    *reinterpret_cast<float4*>(dst + 4) = o1;
}

// ---------------- K3: 1x1 projection GEMM ----------------
__global__ __launch_bounds__(256) void k3_project(
    const float* __restrict__ vout_base,  // [B][CQK][HW]
    const float* __restrict__ wo,         // [64][CQK]
    const float* __restrict__ bo,         // [64]
    float* __restrict__ out_base,         // [B][64][HW]
    size_t vout_bstride, size_t out_bstride)
{
    __shared__ float vsh[CQK][64];
    __shared__ float wsh[CQK][64];
    const float* vout = vout_base + blockIdx.z * vout_bstride;
    float* out        = out_base + blockIdx.z * out_bstride;
    const int pxbase = blockIdx.x * 64;
    const int tid = threadIdx.x;

    #pragma unroll
    for (int r = 0; r < 8; ++r) {
        int idx = r * 256 + tid;
        int cc = idx >> 4;
        int p4 = idx & 15;
        *reinterpret_cast<float4*>(&vsh[cc][p4 * 4]) =
            *reinterpret_cast<const float4*>(&vout[(size_t)cc * HW + pxbase + p4 * 4]);
    }
    #pragma unroll
    for (int r = 0; r < 32; ++r) {
        int idx = r * 256 + tid;
        int cc = idx >> 6;
        int co = idx & 63;
        wsh[cc][co] = wo[co * CQK + cc];
    }
    __syncthreads();

    const int p = tid & 15, g = tid >> 4;
    const int px0 = p * 4, co0 = g * 4;

    float acc[4][4];
    #pragma unroll
    for (int i = 0; i < 4; ++i)
        #pragma unroll
        for (int j = 0; j < 4; ++j) acc[i][j] = 0.f;

    #pragma unroll 4
    for (int cc = 0; cc < CQK; ++cc) {
        float4 xv = *reinterpret_cast<const float4*>(&vsh[cc][px0]);
        float4 wv = *reinterpret_cast<const float4*>(&wsh[cc][co0]);
        float wr[4] = {wv.x, wv.y, wv.z, wv.w};
        float xr[4] = {xv.x, xv.y, xv.z, xv.w};
        #pragma unroll
        for (int i = 0; i < 4; ++i)
            #pragma unroll
            for (int j = 0; j < 4; ++j)
                acc[i][j] += wr[i] * xr[j];
    }
    #pragma unroll
    for (int i = 0; i < 4; ++i) {
        int co = co0 + i;
        float b = bo[co];
        float4 o;
        o.x = acc[i][0] + b; o.y = acc[i][1] + b;
        o.z = acc[i][2] + b; o.w = acc[i][3] + b;
        *reinterpret_cast<float4*>(&out[(size_t)co * HW + pxbase + px0]) = o;
    }
}

extern "C" void kernel_launch(void* const* d_in, const int* in_sizes, int n_in,
                              void* d_out, int out_size, void* d_ws, size_t ws_size,
                              hipStream_t stream) {
    const float* x   = (const float*)d_in[0];
    const float* wh  = (const float*)d_in[1];
    const float* bh  = (const float*)d_in[2];
    const float* wdw = (const float*)d_in[3];
    const float* bdw = (const float*)d_in[4];
    const float* wo  = (const float*)d_in[5];
    const float* bo  = (const float*)d_in[6];
    float* out = (float*)d_out;

    const size_t n_hid  = (size_t)CHID * HW;
    const size_t n_vout = (size_t)CQK * HW;
    const size_t n_x    = (size_t)CIN * HW;

    if (ws_size >= 4 * (n_hid + n_vout) * sizeof(float)) {
        // batched: all 4 images per dispatch via blockIdx.z
        float* hidden = (float*)d_ws;
        float* vout   = hidden + 4 * n_hid;
        k1_expand <<<dim3(HW / 128, CHID / 64, 4), 256, 0, stream>>>(
            x, wh, bh, hidden, n_x, n_hid);
        k2_fused  <<<dim3(H_IMG / 8, CQK, 4),      256, 0, stream>>>(
            hidden, wdw, bdw, vout, n_hid, n_vout);
        k3_project<<<dim3(HW / 64, 1, 4),          256, 0, stream>>>(
            vout, wo, bo, out, n_vout, n_x);
    } else {
        float* hidden = (float*)d_ws;
        float* vout   = hidden + n_hid;
        for (int b = 0; b < 4; ++b) {
            const float* xb = x + (size_t)b * n_x;
            float* ob       = out + (size_t)b * n_x;
            k1_expand <<<dim3(HW / 128, CHID / 64, 1), 256, 0, stream>>>(
                xb, wh, bh, hidden, 0, 0);
            k2_fused  <<<dim3(H_IMG / 8, CQK, 1),      256, 0, stream>>>(
                hidden, wdw, bdw, vout, 0, 0);
            k3_project<<<dim3(HW / 64, 1, 1),          256, 0, stream>>>(
                vout, wo, bo, ob, 0, 0);
        }
    }
}

// Round 3
// 485.864 us; speedup vs baseline: 1.9176x; 1.3175x over previous
//
#include <hip/hip_runtime.h>

#define HW 65536
#define W_IMG 256
#define H_IMG 256
#define CIN 64
#define CHID 384
#define CQK 128

// ---------------- K1: 1x1 expansion GEMM ----------------
__global__ __launch_bounds__(256) void k1_expand(
    const float* __restrict__ x_base,    // [B][CIN][HW]
    const float* __restrict__ wh,        // [CHID][CIN]
    const float* __restrict__ bh,        // [CHID]
    float* __restrict__ hidden_base,     // [B][CHID][HW]
    size_t x_bstride, size_t hid_bstride)
{
    __shared__ float xs[CIN][128];
    __shared__ float wst[CIN][64];
    const float* x = x_base + blockIdx.z * x_bstride;
    float* hidden  = hidden_base + blockIdx.z * hid_bstride;
    const int pxbase = blockIdx.x * 128;
    const int cobase = blockIdx.y * 64;
    const int tid = threadIdx.x;

    #pragma unroll
    for (int r = 0; r < 8; ++r) {
        int idx = r * 256 + tid;
        int ci = idx >> 5;
        int p4 = idx & 31;
        float4 v = *reinterpret_cast<const float4*>(&x[(size_t)ci * HW + pxbase + p4 * 4]);
        *reinterpret_cast<float4*>(&xs[ci][p4 * 4]) = v;
    }
    #pragma unroll
    for (int r = 0; r < 16; ++r) {
        int idx = r * 256 + tid;
        int ci = idx >> 6;
        int co = idx & 63;
        wst[ci][co] = wh[(cobase + co) * CIN + ci];
    }
    __syncthreads();

    const int p = tid & 31;
    const int g = tid >> 5;
    const int px0 = p * 4;
    const int co0 = g * 8;

    float acc[8][4];
    #pragma unroll
    for (int i = 0; i < 8; ++i)
        #pragma unroll
        for (int j = 0; j < 4; ++j) acc[i][j] = 0.f;

    #pragma unroll 4
    for (int ci = 0; ci < CIN; ++ci) {
        float4 xv = *reinterpret_cast<const float4*>(&xs[ci][px0]);
        float4 w0 = *reinterpret_cast<const float4*>(&wst[ci][co0]);
        float4 w1 = *reinterpret_cast<const float4*>(&wst[ci][co0 + 4]);
        float wr[8] = {w0.x, w0.y, w0.z, w0.w, w1.x, w1.y, w1.z, w1.w};
        float xr[4] = {xv.x, xv.y, xv.z, xv.w};
        #pragma unroll
        for (int i = 0; i < 8; ++i)
            #pragma unroll
            for (int j = 0; j < 4; ++j)
                acc[i][j] += wr[i] * xr[j];
    }
    #pragma unroll
    for (int i = 0; i < 8; ++i) {
        int co = cobase + co0 + i;
        float b = bh[co];
        float4 o;
        o.x = acc[i][0] + b; o.y = acc[i][1] + b;
        o.z = acc[i][2] + b; o.w = acc[i][3] + b;
        *reinterpret_cast<float4*>(&hidden[(size_t)co * HW + pxbase + px0]) = o;
    }
}

// ---------------- K2: fused depthwise 3x3 + 8x8 circular conv + v-mul ----------------
// block = (strip of 8 rows, channel c); 256 threads.
// v3: bulk-stage q,k hidden rows into LDS (float4 coalesced), depthwise from LDS,
//     v-channel loads hoisted ahead of the circular-conv compute.
__global__ __launch_bounds__(256) void k2_fused(
    const float* __restrict__ hidden_base,  // [B][CHID][HW]
    const float* __restrict__ wdw,          // [CHID][9]
    const float* __restrict__ bdw,          // [CHID]
    float* __restrict__ vout_base,          // [B][CQK][HW]
    size_t hid_bstride, size_t vout_bstride)
{
    __shared__ float stg[2][10][260];    // raw hidden rows for q,k (stride 260)
    __shared__ float qk[2][8][4][68];    // depthwise output (padded strides)

    const float* hidden = hidden_base + blockIdx.z * hid_bstride;
    float* vout         = vout_base + blockIdx.z * vout_bstride;

    const int c  = blockIdx.y;          // qkv channel 0..127
    const int r0 = blockIdx.x * 8;
    const int tid = threadIdx.x;

    // ---- phase 0: coalesced stage of q,k hidden rows (rows r0-1 .. r0+8)
    #pragma unroll
    for (int it = 0; it < 5; ++it) {
        int f4  = it * 256 + tid;       // 0..1279
        int ch  = f4 / 640;
        int rem = f4 - ch * 640;
        int lr  = rem >> 6;             // 0..9
        int p4  = rem & 63;
        int gr  = r0 - 1 + lr;
        float4 v = make_float4(0.f, 0.f, 0.f, 0.f);
        if ((unsigned)gr < H_IMG)
            v = *reinterpret_cast<const float4*>(
                &hidden[(size_t)(c + ch * CQK) * HW + (size_t)gr * W_IMG + p4 * 4]);
        *reinterpret_cast<float4*>(&stg[ch][lr][p4 * 4]) = v;
    }
    __syncthreads();

    // ---- phase 1: depthwise 3x3 from LDS -> qk
    const int w = tid;
    const int segw = w >> 6;
    const int tw   = w & 63;
    #pragma unroll
    for (int ch = 0; ch < 2; ++ch) {
        const float* wv = wdw + (c + ch * CQK) * 9;   // block-uniform -> scalar loads
        const float bias = bdw[c + ch * CQK];
        const float w0 = wv[0], w1 = wv[1], w2 = wv[2];
        const float w3 = wv[3], w4 = wv[4], w5 = wv[5];
        const float w6 = wv[6], w7 = wv[7], w8 = wv[8];
        const float* S = &stg[ch][0][0];

        float am, a0, ap, bm, b0, bp;
        a0 = S[w];
        am = (w > 0)   ? S[w - 1] : 0.f;
        ap = (w < 255) ? S[w + 1] : 0.f;
        b0 = S[260 + w];
        bm = (w > 0)   ? S[260 + w - 1] : 0.f;
        bp = (w < 255) ? S[260 + w + 1] : 0.f;

        #pragma unroll
        for (int r = 0; r < 8; ++r) {
            const float* Sr = S + (r + 2) * 260;
            float c0 = Sr[w];
            float cm = (w > 0)   ? Sr[w - 1] : 0.f;
            float cp = (w < 255) ? Sr[w + 1] : 0.f;
            float a = bias + am * w0 + a0 * w1 + ap * w2
                           + bm * w3 + b0 * w4 + bp * w5
                           + cm * w6 + c0 * w7 + cp * w8;
            qk[ch][r][segw][tw] = a;
            am = bm; a0 = b0; ap = bp;
            bm = cm; b0 = c0; bp = cp;
        }
    }
    __syncthreads();

    // ---- phase 2: hoisted v loads, 8x8 circular conv, v depthwise, multiply
    const int row = tid >> 5;           // 0..7
    const int seg = (tid >> 3) & 3;     // 0..3
    const int i   = tid & 7;            // output patch-row
    const int gr  = r0 + row;
    const int wp0 = seg * 64 + i * 8;

    // hoist v-channel global loads (latency hides under the conv below)
    const float* hbv = hidden + (size_t)(c + 2 * CQK) * HW;
    float4 hv[3][2];
    float  hm[3], hp[3];
    #pragma unroll
    for (int ky = 0; ky < 3; ++ky) {
        int grr = gr + ky - 1;
        hv[ky][0] = make_float4(0.f, 0.f, 0.f, 0.f);
        hv[ky][1] = make_float4(0.f, 0.f, 0.f, 0.f);
        hm[ky] = 0.f; hp[ky] = 0.f;
        if ((unsigned)grr < H_IMG) {
            const float* rb = hbv + (size_t)grr * W_IMG;
            hv[ky][0] = *reinterpret_cast<const float4*>(&rb[wp0]);
            hv[ky][1] = *reinterpret_cast<const float4*>(&rb[wp0 + 4]);
            hm[ky] = (wp0 > 0)   ? rb[wp0 - 1] : 0.f;
            hp[ky] = (wp0 < 248) ? rb[wp0 + 8] : 0.f;
        }
    }

    const float* qb = &qk[0][row][seg][0];
    const float* kb = &qk[1][row][seg][0];

    float acc[8];
    #pragma unroll
    for (int j = 0; j < 8; ++j) acc[j] = 0.f;

    #pragma unroll
    for (int s = 0; s < 8; ++s) {
        int qr = (i - s) & 7;
        float4 ka = *reinterpret_cast<const float4*>(&kb[s * 8]);
        float4 kc = *reinterpret_cast<const float4*>(&kb[s * 8 + 4]);
        float4 qa = *reinterpret_cast<const float4*>(&qb[qr * 8]);
        float4 qc = *reinterpret_cast<const float4*>(&qb[qr * 8 + 4]);
        float kr[8] = {ka.x, ka.y, ka.z, ka.w, kc.x, kc.y, kc.z, kc.w};
        float qv[8] = {qa.x, qa.y, qa.z, qa.w, qc.x, qc.y, qc.z, qc.w};
        #pragma unroll
        for (int t = 0; t < 8; ++t)
            #pragma unroll
            for (int j = 0; j < 8; ++j)
                acc[j] += kr[t] * qv[(j - t) & 7];
    }

    // v depthwise from hoisted registers
    const float* wvv = wdw + (c + 2 * CQK) * 9;
    const float vbias = bdw[c + 2 * CQK];
    float vc[8];
    #pragma unroll
    for (int j = 0; j < 8; ++j) vc[j] = vbias;
    #pragma unroll
    for (int ky = 0; ky < 3; ++ky) {
        float kw0 = wvv[ky * 3], kw1 = wvv[ky * 3 + 1], kw2 = wvv[ky * 3 + 2];
        float h[10];
        h[0] = hm[ky];
        h[1] = hv[ky][0].x; h[2] = hv[ky][0].y; h[3] = hv[ky][0].z; h[4] = hv[ky][0].w;
        h[5] = hv[ky][1].x; h[6] = hv[ky][1].y; h[7] = hv[ky][1].z; h[8] = hv[ky][1].w;
        h[9] = hp[ky];
        #pragma unroll
        for (int j = 0; j < 8; ++j)
            vc[j] += h[j] * kw0 + h[j + 1] * kw1 + h[j + 2] * kw2;
    }

    float* dst = &vout[(size_t)c * HW + (size_t)gr * W_IMG + wp0];
    float4 o0, o1;
    o0.x = acc[0] * vc[0]; o0.y = acc[1] * vc[1];
    o0.z = acc[2] * vc[2]; o0.w = acc[3] * vc[3];
    o1.x = acc[4] * vc[4]; o1.y = acc[5] * vc[5];
    o1.z = acc[6] * vc[6]; o1.w = acc[7] * vc[7];
    *reinterpret_cast<float4*>(dst)     = o0;
    *reinterpret_cast<float4*>(dst + 4) = o1;
}

// ---------------- K3: 1x1 projection GEMM ----------------
__global__ __launch_bounds__(256) void k3_project(
    const float* __restrict__ vout_base,  // [B][CQK][HW]
    const float* __restrict__ wo,         // [64][CQK]
    const float* __restrict__ bo,         // [64]
    float* __restrict__ out_base,         // [B][64][HW]
    size_t vout_bstride, size_t out_bstride)
{
    __shared__ float vsh[CQK][64];
    __shared__ float wsh[CQK][64];
    const float* vout = vout_base + blockIdx.z * vout_bstride;
    float* out        = out_base + blockIdx.z * out_bstride;
    const int pxbase = blockIdx.x * 64;
    const int tid = threadIdx.x;

    #pragma unroll
    for (int r = 0; r < 8; ++r) {
        int idx = r * 256 + tid;
        int cc = idx >> 4;
        int p4 = idx & 15;
        *reinterpret_cast<float4*>(&vsh[cc][p4 * 4]) =
            *reinterpret_cast<const float4*>(&vout[(size_t)cc * HW + pxbase + p4 * 4]);
    }
    #pragma unroll
    for (int r = 0; r < 32; ++r) {
        int idx = r * 256 + tid;
        int cc = idx >> 6;
        int co = idx & 63;
        wsh[cc][co] = wo[co * CQK + cc];
    }
    __syncthreads();

    const int p = tid & 15, g = tid >> 4;
    const int px0 = p * 4, co0 = g * 4;

    float acc[4][4];
    #pragma unroll
    for (int i = 0; i < 4; ++i)
        #pragma unroll
        for (int j = 0; j < 4; ++j) acc[i][j] = 0.f;

    #pragma unroll 4
    for (int cc = 0; cc < CQK; ++cc) {
        float4 xv = *reinterpret_cast<const float4*>(&vsh[cc][px0]);
        float4 wv = *reinterpret_cast<const float4*>(&wsh[cc][co0]);
        float wr[4] = {wv.x, wv.y, wv.z, wv.w};
        float xr[4] = {xv.x, xv.y, xv.z, xv.w};
        #pragma unroll
        for (int i = 0; i < 4; ++i)
            #pragma unroll
            for (int j = 0; j < 4; ++j)
                acc[i][j] += wr[i] * xr[j];
    }
    #pragma unroll
    for (int i = 0; i < 4; ++i) {
        int co = co0 + i;
        float b = bo[co];
        float4 o;
        o.x = acc[i][0] + b; o.y = acc[i][1] + b;
        o.z = acc[i][2] + b; o.w = acc[i][3] + b;
        *reinterpret_cast<float4*>(&out[(size_t)co * HW + pxbase + px0]) = o;
    }
}

extern "C" void kernel_launch(void* const* d_in, const int* in_sizes, int n_in,
                              void* d_out, int out_size, void* d_ws, size_t ws_size,
                              hipStream_t stream) {
    const float* x   = (const float*)d_in[0];
    const float* wh  = (const float*)d_in[1];
    const float* bh  = (const float*)d_in[2];
    const float* wdw = (const float*)d_in[3];
    const float* bdw = (const float*)d_in[4];
    const float* wo  = (const float*)d_in[5];
    const float* bo  = (const float*)d_in[6];
    float* out = (float*)d_out;

    const size_t n_hid  = (size_t)CHID * HW;
    const size_t n_vout = (size_t)CQK * HW;
    const size_t n_x    = (size_t)CIN * HW;

    if (ws_size >= 4 * (n_hid + n_vout) * sizeof(float)) {
        float* hidden = (float*)d_ws;
        float* vout   = hidden + 4 * n_hid;
        k1_expand <<<dim3(HW / 128, CHID / 64, 4), 256, 0, stream>>>(
            x, wh, bh, hidden, n_x, n_hid);
        k2_fused  <<<dim3(H_IMG / 8, CQK, 4),      256, 0, stream>>>(
            hidden, wdw, bdw, vout, n_hid, n_vout);
        k3_project<<<dim3(HW / 64, 1, 4),          256, 0, stream>>>(
            vout, wo, bo, out, n_vout, n_x);
    } else {
        float* hidden = (float*)d_ws;
        float* vout   = hidden + n_hid;
        for (int b = 0; b < 4; ++b) {
            const float* xb = x + (size_t)b * n_x;
            float* ob       = out + (size_t)b * n_x;
            k1_expand <<<dim3(HW / 128, CHID / 64, 1), 256, 0, stream>>>(
                xb, wh, bh, hidden, 0, 0);
            k2_fused  <<<dim3(H_IMG / 8, CQK, 1),      256, 0, stream>>>(
                hidden, wdw, bdw, vout, 0, 0);
            k3_project<<<dim3(HW / 64, 1, 1),          256, 0, stream>>>(
                vout, wo, bo, ob, 0, 0);
        }
    }
}